// Round 2
// baseline (1770.920 us; speedup 1.0000x reference)
//
#include <hip/hip_runtime.h>
#include <hip/hip_bf16.h>
#include <stdint.h>

#define BB 4
#define SS 1024
#define DIM 2048
#define NH 16
#define QR 1024
#define KVR 512
#define NOPE 128
#define ROPE 64
#define VH 128
#define QKH 192
#define NTOK 4096

static constexpr float SCALE_ = 0.07216878364870322f; // 192^-0.5
static constexpr float EPS_ = 1e-6f;

typedef unsigned short u16;
typedef unsigned int u32;
using f32x4  = __attribute__((ext_vector_type(4))) float;
using bf16x8 = __attribute__((ext_vector_type(8))) __bf16;

#define MFMA16 __builtin_amdgcn_mfma_f32_16x16x32_bf16

__device__ __forceinline__ u16 f2b(float f) {
  u32 u = __float_as_uint(f);
  u32 r = u + 0x7fffu + ((u >> 16) & 1u);   // RNE
  return (u16)(r >> 16);
}
__device__ __forceinline__ u32 pk2(float a, float b) {
  return (u32)f2b(a) | ((u32)f2b(b) << 16);
}
__device__ __forceinline__ float b2f(u32 hi16) {
  return __uint_as_float(hi16 << 16);
}

// ---------------- f32 -> bf16 convert (8 elems/thread) ----------------
__global__ __launch_bounds__(256) void cvt_bf16(const float* __restrict__ in,
                                                u16* __restrict__ out, int n) {
  int i = (blockIdx.x * 256 + threadIdx.x) * 8;
  if (i >= n) return;
  float4 a = *(const float4*)&in[i];
  float4 b = *(const float4*)&in[i + 4];
  uint4 o;
  o.x = pk2(a.x, a.y); o.y = pk2(a.z, a.w);
  o.z = pk2(b.x, b.y); o.w = pk2(b.z, b.w);
  *(uint4*)&out[i] = o;
}

// ---------------- wkv_b split: wb_k transposed per head, wb_v straight ----------------
__global__ __launch_bounds__(256) void prep_wkvb(const float* __restrict__ w,
                                                 u16* __restrict__ wbkt,
                                                 u16* __restrict__ wbv) {
  int idx = blockIdx.x * 256 + threadIdx.x;   // over 16*256*512
  int c = idx & 511;
  int rowh = idx >> 9;
  int h = rowh >> 8;
  int dr = rowh & 255;
  float v = w[idx];
  if (dr < NOPE) wbkt[((h * KVR + c) << 7) + dr] = f2b(v);           // (NH,512,128)
  else           wbv[((h * VH + (dr - NOPE)) << 9) + c] = f2b(v);    // (NH,128,512)
}

// ---------------- RMSNorm over 1024 (q path) ----------------
__global__ __launch_bounds__(256) void rms_q_kernel(const float* __restrict__ X,
                                                    const float* __restrict__ w,
                                                    u16* __restrict__ out) {
  int r = blockIdx.x, tid = threadIdx.x;
  const float4 v = *(const float4*)&X[(long)r * QR + tid * 4];
  float ss = v.x * v.x + v.y * v.y + v.z * v.z + v.w * v.w;
  for (int m = 1; m < 64; m <<= 1) ss += __shfl_xor(ss, m);
  __shared__ float red[4];
  if ((tid & 63) == 0) red[tid >> 6] = ss;
  __syncthreads();
  float tot = red[0] + red[1] + red[2] + red[3];
  float sc = rsqrtf(tot / QR + EPS_);
  float4 wv = *(const float4*)&w[tid * 4];
  uint2 o;
  o.x = pk2(v.x * sc * wv.x, v.y * sc * wv.y);
  o.y = pk2(v.z * sc * wv.z, v.w * sc * wv.w);
  *(uint2*)&out[(long)r * QR + tid * 4] = o;
}

// ---------------- q post (bf16 input): split nope / rope(pe), head-major ----------------
__global__ __launch_bounds__(256) void post_q_kernel(const u16* __restrict__ C2,
                                                     const float* __restrict__ fc,
                                                     const float* __restrict__ fs,
                                                     u16* __restrict__ qn,
                                                     u16* __restrict__ qp) {
  int r = blockIdx.x, tid = threadIdx.x;
  int s = r & (SS - 1);
  const u16* row = C2 + (long)r * (NH * QKH);
  for (int j = tid; j < NH * QKH / 2; j += 256) {
    int col = j * 2;
    int h = col / QKH;
    int dd = col - h * QKH;
    u32 pair = *(const u32*)&row[col];
    if (dd < NOPE) {
      *(u32*)&qn[((long)h * NTOK + r) * NOPE + dd] = pair;   // already bf16
    } else {
      float x0 = b2f(pair & 0xffffu), x1 = b2f(pair >> 16);
      int jr = (dd - NOPE) >> 1;
      float c = fc[s * 32 + jr], sn = fs[s * 32 + jr];
      *(u32*)&qp[((long)h * NTOK + r) * ROPE + (dd - NOPE)] =
          pk2(x0 * c - x1 * sn, x0 * sn + x1 * c);
    }
  }
}

// ---------------- kv post: rmsnorm(512) -> kv + kv^T, rope k_pe ----------------
__global__ __launch_bounds__(256) void post_kv_kernel(const float* __restrict__ C3,
                                                      const float* __restrict__ w,
                                                      const float* __restrict__ fc,
                                                      const float* __restrict__ fs,
                                                      u16* __restrict__ kv,
                                                      u16* __restrict__ kvt,
                                                      u16* __restrict__ kpe) {
  int r = blockIdx.x, tid = threadIdx.x;
  int b = r >> 10, t = r & (SS - 1);
  const float* row = C3 + (long)r * 576;
  float2 v = *(const float2*)&row[tid * 2];
  float ss = v.x * v.x + v.y * v.y;
  for (int m = 1; m < 64; m <<= 1) ss += __shfl_xor(ss, m);
  __shared__ float red[4];
  if ((tid & 63) == 0) red[tid >> 6] = ss;
  __syncthreads();
  float tot = red[0] + red[1] + red[2] + red[3];
  float sc = rsqrtf(tot / KVR + EPS_);
  int c = tid * 2;
  float y0 = v.x * sc * w[c], y1 = v.y * sc * w[c + 1];
  *(u32*)&kv[((long)b * SS + t) * KVR + c] = pk2(y0, y1);
  kvt[((long)b * KVR + c) * SS + t] = f2b(y0);
  kvt[((long)b * KVR + c + 1) * SS + t] = f2b(y1);
  if (tid < 32) {
    float x0 = row[KVR + tid * 2], x1 = row[KVR + tid * 2 + 1];
    float cc = fc[t * 32 + tid], sn = fs[t * 32 + tid];
    *(u32*)&kpe[((long)b * SS + t) * ROPE + tid * 2] =
        pk2(x0 * cc - x1 * sn, x0 * sn + x1 * cc);
  }
}

// ---------------- GEMM: C(M,N) = A(M,K) * B(N,K)^T, bf16 in, f32/bf16 out ----------------
// 128x128 tile, BK=32, 4 waves, double-buffered LDS via global_load_lds width 16.
template <bool CBF16>
__global__ __launch_bounds__(256) void gemm_bt(const u16* __restrict__ Ag,
                                               const u16* __restrict__ Bg,
                                               void* __restrict__ Cg,
                                               int M, int N, int K,
                                               int lda, int ldb, int ldc,
                                               long sA, long sB, long sC) {
  const u16* A = Ag + (long)blockIdx.z * sA;
  const u16* Bm = Bg + (long)blockIdx.z * sB;
  const int row0 = blockIdx.y * 128;
  const int col0 = blockIdx.x * 128;
  const int tid = threadIdx.x;
  const int wave = tid >> 6, lane = tid & 63;
  const int g = lane >> 4, r = lane & 15;
  const int wr = wave >> 1, wc = wave & 1;

  __shared__ u16 As[2][128 * 32];
  __shared__ u16 Bs[2][128 * 32];

  f32x4 acc[4][4] = {};
  const int nk = K >> 5;

  auto stage = [&](int kt, int p) {
    int k0 = kt << 5;
#pragma unroll
    for (int j = 0; j < 2; ++j) {
      int ldsoff = (j * 4096 + wave * 1024) >> 1;   // bytes -> elements, wave-uniform
      int rowi = j * 64 + wave * 16 + (lane >> 2);
      int coli = (lane & 3) << 3;
      const u16* ga = A + (long)(row0 + rowi) * lda + k0 + coli;
      __builtin_amdgcn_global_load_lds(
          (const __attribute__((address_space(1))) void*)ga,
          (__attribute__((address_space(3))) void*)(&As[p][ldsoff]), 16, 0, 0);
      int rb = col0 + rowi; if (rb > N - 1) rb = N - 1;
      const u16* gb = Bm + (long)rb * ldb + k0 + coli;
      __builtin_amdgcn_global_load_lds(
          (const __attribute__((address_space(1))) void*)gb,
          (__attribute__((address_space(3))) void*)(&Bs[p][ldsoff]), 16, 0, 0);
    }
  };

  stage(0, 0);
  for (int kt = 0; kt < nk; ++kt) {
    __syncthreads();
    if (kt + 1 < nk) stage(kt + 1, (kt + 1) & 1);
    const int p = kt & 1;
    bf16x8 af[4], bf[4];
#pragma unroll
    for (int i = 0; i < 4; i++) {
      af[i] = *(const bf16x8*)&As[p][(wr * 64 + i * 16 + r) * 32 + g * 8];
      bf[i] = *(const bf16x8*)&Bs[p][(wc * 64 + i * 16 + r) * 32 + g * 8];
    }
#pragma unroll
    for (int i = 0; i < 4; i++)
#pragma unroll
      for (int j = 0; j < 4; j++)
        acc[i][j] = MFMA16(af[i], bf[j], acc[i][j], 0, 0, 0);
  }

#pragma unroll
  for (int i = 0; i < 4; i++)
#pragma unroll
    for (int j = 0; j < 4; j++) {
      int rowb = row0 + wr * 64 + i * 16 + g * 4;
      int colc = col0 + wc * 64 + j * 16 + r;
      if (colc < N) {
        if constexpr (CBF16) {
          u16* C = (u16*)Cg + (long)blockIdx.z * sC;
#pragma unroll
          for (int e = 0; e < 4; e++)
            C[(long)(rowb + e) * ldc + colc] = f2b(acc[i][j][e]);
        } else {
          float* C = (float*)Cg + (long)blockIdx.z * sC;
#pragma unroll
          for (int e = 0; e < 4; e++)
            C[(long)(rowb + e) * ldc + colc] = acc[i][j][e];
        }
      }
    }
}

// ---------------- flash attention: 4 indep waves, 16 q-rows/wave, 32-key tiles ----------------
__global__ __launch_bounds__(256) void attn_kernel(const u16* __restrict__ q_lat,
                                                   const u16* __restrict__ q_pe,
                                                   const u16* __restrict__ kv,
                                                   const u16* __restrict__ kvt,
                                                   const u16* __restrict__ kpe,
                                                   u16* __restrict__ o_lat) {
  const int h = blockIdx.y, b = blockIdx.z;
  const int wave = threadIdx.x >> 6, lane = threadIdx.x & 63;
  const int g = lane >> 4, r = lane & 15;
  const int qb = blockIdx.x * 64 + wave * 16;

  const u16* Q  = q_lat + ((long)h * NTOK + (long)b * SS + qb) * KVR;
  const u16* Qp = q_pe  + ((long)h * NTOK + (long)b * SS + qb) * ROPE;
  const u16* KV = kv  + (long)b * SS * KVR;
  const u16* KT = kvt + (long)b * KVR * SS;
  const u16* KP = kpe + (long)b * SS * ROPE;

  f32x4 acc[32];
#pragma unroll
  for (int i = 0; i < 32; i++) acc[i] = f32x4{0.f, 0.f, 0.f, 0.f};
  float m_run = -1e30f, l_run = 0.f;
  __shared__ __attribute__((aligned(16))) u16 P[4][16][40];

  const int q_lane = qb + r;
  const int ntile = (qb + 47) >> 5;

  for (int tt = 0; tt < ntile; ++tt) {
    const int t0 = tt * 32;
    f32x4 st0 = {0.f, 0.f, 0.f, 0.f}, st1 = {0.f, 0.f, 0.f, 0.f};
#pragma unroll
    for (int d0 = 0; d0 < KVR; d0 += 32) {
      bf16x8 qf = *(const bf16x8*)&Q[r * KVR + d0 + g * 8];
      bf16x8 k0 = *(const bf16x8*)&KV[(t0 + r) * KVR + d0 + g * 8];
      bf16x8 k1 = *(const bf16x8*)&KV[(t0 + 16 + r) * KVR + d0 + g * 8];
      st0 = MFMA16(k0, qf, st0, 0, 0, 0);
      st1 = MFMA16(k1, qf, st1, 0, 0, 0);
    }
#pragma unroll
    for (int d0 = 0; d0 < ROPE; d0 += 32) {
      bf16x8 qf = *(const bf16x8*)&Qp[r * ROPE + d0 + g * 8];
      bf16x8 k0 = *(const bf16x8*)&KP[(t0 + r) * ROPE + d0 + g * 8];
      bf16x8 k1 = *(const bf16x8*)&KP[(t0 + 16 + r) * ROPE + d0 + g * 8];
      st0 = MFMA16(k0, qf, st0, 0, 0, 0);
      st1 = MFMA16(k1, qf, st1, 0, 0, 0);
    }
    // softmax (lane stats are for query qb+r; reduce over 4 lanes with same r)
    float sv[8];
    float smax = -1e30f;
#pragma unroll
    for (int i = 0; i < 4; i++) {
      int t = t0 + g * 4 + i;
      sv[i]     = (t      <= q_lane) ? st0[i] * SCALE_ : -1e30f;
      sv[4 + i] = (t + 16 <= q_lane) ? st1[i] * SCALE_ : -1e30f;
      smax = fmaxf(smax, fmaxf(sv[i], sv[4 + i]));
    }
    smax = fmaxf(smax, __shfl_xor(smax, 16));
    smax = fmaxf(smax, __shfl_xor(smax, 32));
    float m_new = fmaxf(m_run, smax);
    float alpha = __expf(m_run - m_new);
    float p[8], ps = 0.f;
#pragma unroll
    for (int i = 0; i < 8; i++) { p[i] = __expf(sv[i] - m_new); ps += p[i]; }
    ps += __shfl_xor(ps, 16);
    ps += __shfl_xor(ps, 32);
    l_run = l_run * alpha + ps;
    m_run = m_new;
    float a0 = __shfl(alpha, g * 4 + 0);
    float a1 = __shfl(alpha, g * 4 + 1);
    float a2 = __shfl(alpha, g * 4 + 2);
    float a3 = __shfl(alpha, g * 4 + 3);
#pragma unroll
    for (int i = 0; i < 32; i++) {
      acc[i][0] *= a0; acc[i][1] *= a1; acc[i][2] *= a2; acc[i][3] *= a3;
    }
    // P -> LDS (bf16), re-fragment for PV
    *(u32*)&P[wave][r][g * 4]          = pk2(p[0], p[1]);
    *(u32*)&P[wave][r][g * 4 + 2]      = pk2(p[2], p[3]);
    *(u32*)&P[wave][r][16 + g * 4]     = pk2(p[4], p[5]);
    *(u32*)&P[wave][r][16 + g * 4 + 2] = pk2(p[6], p[7]);
    asm volatile("" ::: "memory");
    bf16x8 pf = *(const bf16x8*)&P[wave][r][g * 8];
    asm volatile("" ::: "memory");
#pragma unroll
    for (int cf = 0; cf < 32; ++cf) {
      bf16x8 vf = *(const bf16x8*)&KT[(cf * 16 + r) * SS + t0 + g * 8];
      acc[cf] = MFMA16(pf, vf, acc[cf], 0, 0, 0);
    }
    asm volatile("" ::: "memory");
  }

  float inv = 1.f / l_run;
  float i0 = __shfl(inv, g * 4 + 0);
  float i1 = __shfl(inv, g * 4 + 1);
  float i2 = __shfl(inv, g * 4 + 2);
  float i3 = __shfl(inv, g * 4 + 3);
  u16* O = o_lat + ((long)h * NTOK + (long)b * SS + qb) * KVR;
#pragma unroll
  for (int cf = 0; cf < 32; ++cf) {
    int cc = cf * 16 + r;
    O[(g * 4 + 0) * KVR + cc] = f2b(acc[cf][0] * i0);
    O[(g * 4 + 1) * KVR + cc] = f2b(acc[cf][1] * i1);
    O[(g * 4 + 2) * KVR + cc] = f2b(acc[cf][2] * i2);
    O[(g * 4 + 3) * KVR + cc] = f2b(acc[cf][3] * i3);
  }
}

// ---------------- host launch ----------------
extern "C" void kernel_launch(void* const* d_in, const int* in_sizes, int n_in,
                              void* d_out, int out_size, void* d_ws, size_t ws_size,
                              hipStream_t stream) {
  (void)in_sizes; (void)n_in; (void)out_size; (void)ws_size;
  const float* x    = (const float*)d_in[0];
  const float* fc   = (const float*)d_in[2];
  const float* fs   = (const float*)d_in[3];
  const float* wqa  = (const float*)d_in[4];
  const float* qnw  = (const float*)d_in[5];
  const float* wqb  = (const float*)d_in[6];
  const float* wkva = (const float*)d_in[7];
  const float* kvnw = (const float*)d_in[8];
  const float* wkvb = (const float*)d_in[9];
  const float* wo   = (const float*)d_in[10];
  float* out = (float*)d_out;

  char* w = (char*)d_ws;
  size_t off = 0;
  auto alloc = [&](size_t bytes) {
    void* p = w + off;
    off += (bytes + 255) & ~(size_t)255;
    return p;
  };
  // ---- persistent region (~60.5 MB) ----
  u16* wbkt   = (u16*)alloc((size_t)NH * KVR * NOPE * 2);
  u16* wbv    = (u16*)alloc((size_t)NH * VH * KVR * 2);
  u16* wo_b   = (u16*)alloc((size_t)DIM * DIM * 2);
  u16* qnope  = (u16*)alloc((size_t)NH * NTOK * NOPE * 2);
  u16* qpe    = (u16*)alloc((size_t)NH * NTOK * ROPE * 2);
  u16* kvb    = (u16*)alloc((size_t)BB * SS * KVR * 2);
  u16* kvt    = (u16*)alloc((size_t)BB * KVR * SS * 2);
  u16* kpe    = (u16*)alloc((size_t)BB * SS * ROPE * 2);
  u16* oflat  = (u16*)alloc((size_t)NTOK * DIM * 2);
  // ---- transient region (~80 MB), later overlaid by qlat/olat (64 MB) ----
  u16* qlat   = (u16*)(w + off);            // overlay base
  u16* olat   = qlat;                       // attention writes O in-place over Q
  u16* x_bf   = (u16*)alloc((size_t)NTOK * DIM * 2);
  u16* wqa_b  = (u16*)alloc((size_t)QR * DIM * 2);
  u16* wqb_b  = (u16*)alloc((size_t)NH * QKH * QR * 2);
  u16* wkva_b = (u16*)alloc((size_t)576 * DIM * 2);
  u16* qn     = (u16*)alloc((size_t)NTOK * QR * 2);
  float* C1   = (float*)alloc((size_t)NTOK * QR * 4);        // q_a f32; reused for kv_full (4096x576)
  u16* C2b    = (u16*)alloc((size_t)NTOK * NH * QKH * 2);    // q as bf16

  cvt_bf16<<<(NTOK * DIM) / 2048, 256, 0, stream>>>(x, x_bf, NTOK * DIM);
  cvt_bf16<<<(QR * DIM) / 2048, 256, 0, stream>>>(wqa, wqa_b, QR * DIM);
  cvt_bf16<<<(NH * QKH * QR) / 2048, 256, 0, stream>>>(wqb, wqb_b, NH * QKH * QR);
  cvt_bf16<<<(576 * DIM) / 2048, 256, 0, stream>>>(wkva, wkva_b, 576 * DIM);
  cvt_bf16<<<(DIM * DIM) / 2048, 256, 0, stream>>>(wo, wo_b, DIM * DIM);
  prep_wkvb<<<(NH * 256 * KVR) / 256, 256, 0, stream>>>(wkvb, wbkt, wbv);

  // q_a = x @ wq_a^T  (4096 x 1024, K=2048)
  gemm_bt<false><<<dim3(QR / 128, NTOK / 128, 1), 256, 0, stream>>>(
      x_bf, wqa_b, C1, NTOK, QR, DIM, DIM, DIM, QR, 0, 0, 0);
  rms_q_kernel<<<NTOK, 256, 0, stream>>>(C1, qnw, qn);
  // q = qn @ wq_b^T  (4096 x 3072, K=1024) -> bf16
  gemm_bt<true><<<dim3(NH * QKH / 128, NTOK / 128, 1), 256, 0, stream>>>(
      qn, wqb_b, C2b, NTOK, NH * QKH, QR, QR, QR, NH * QKH, 0, 0, 0);
  post_q_kernel<<<NTOK, 256, 0, stream>>>(C2b, fc, fs, qnope, qpe);
  // kv_full = x @ wkv_a^T  (4096 x 576, K=2048)
  gemm_bt<false><<<dim3(5, NTOK / 128, 1), 256, 0, stream>>>(
      x_bf, wkva_b, C1, NTOK, 576, DIM, DIM, DIM, 576, 0, 0, 0);
  post_kv_kernel<<<NTOK, 256, 0, stream>>>(C1, kvnw, fc, fs, kvb, kvt, kpe);
  // q_lat[h] = q_nope[h] @ wb_k[h]^T  (per-head 4096 x 512, K=128)
  // NOTE: overwrites the transient region — all its consumers are done by here.
  gemm_bt<true><<<dim3(KVR / 128, NTOK / 128, NH), 256, 0, stream>>>(
      qnope, wbkt, qlat, NTOK, KVR, NOPE, NOPE, NOPE, KVR,
      (long)NTOK * NOPE, (long)KVR * NOPE, (long)NTOK * KVR);
  // attention (O written in-place over Q slice; block-local rows only)
  attn_kernel<<<dim3(SS / 64, NH, BB), 256, 0, stream>>>(qlat, qpe, kvb, kvt, kpe, olat);
  // o_head[h] = o_lat[h] @ wb_v[h]^T  (4096 x 128, K=512) -> packed into oflat cols h*128
  gemm_bt<true><<<dim3(1, NTOK / 128, NH), 256, 0, stream>>>(
      olat, wbv, oflat, NTOK, VH, KVR, KVR, KVR, DIM,
      (long)NTOK * KVR, (long)VH * KVR, (long)VH);
  // out = oflat @ wo^T  (4096 x 2048, K=2048)
  gemm_bt<false><<<dim3(DIM / 128, NTOK / 128, 1), 256, 0, stream>>>(
      oflat, wo_b, out, NTOK, DIM, DIM, DIM, DIM, DIM, 0, 0, 0);
}

// Round 3
// 958.394 us; speedup vs baseline: 1.8478x; 1.8478x over previous
//
#include <hip/hip_runtime.h>
#include <hip/hip_bf16.h>
#include <stdint.h>

#define BB 4
#define SS 1024
#define DIM 2048
#define NH 16
#define QR 1024
#define KVR 512
#define NOPE 128
#define ROPE 64
#define VH 128
#define QKH 192
#define NTOK 4096

static constexpr float SCALE_ = 0.07216878364870322f; // 192^-0.5
static constexpr float EPS_ = 1e-6f;

typedef unsigned short u16;
typedef unsigned int u32;
using f32x4  = __attribute__((ext_vector_type(4))) float;
using bf16x8 = __attribute__((ext_vector_type(8))) __bf16;

#define MFMA16 __builtin_amdgcn_mfma_f32_16x16x32_bf16

__device__ __forceinline__ u16 f2b(float f) {
  u32 u = __float_as_uint(f);
  u32 r = u + 0x7fffu + ((u >> 16) & 1u);   // RNE
  return (u16)(r >> 16);
}
__device__ __forceinline__ u32 pk2(float a, float b) {
  return (u32)f2b(a) | ((u32)f2b(b) << 16);
}
__device__ __forceinline__ float b2f(u32 hi16) {
  return __uint_as_float(hi16 << 16);
}

// ---------------- f32 -> bf16 convert (8 elems/thread) ----------------
__global__ __launch_bounds__(256) void cvt_bf16(const float* __restrict__ in,
                                                u16* __restrict__ out, int n) {
  int i = (blockIdx.x * 256 + threadIdx.x) * 8;
  if (i >= n) return;
  float4 a = *(const float4*)&in[i];
  float4 b = *(const float4*)&in[i + 4];
  uint4 o;
  o.x = pk2(a.x, a.y); o.y = pk2(a.z, a.w);
  o.z = pk2(b.x, b.y); o.w = pk2(b.z, b.w);
  *(uint4*)&out[i] = o;
}

// ---------------- wkv_b split: wb_k transposed per head, wb_v straight ----------------
__global__ __launch_bounds__(256) void prep_wkvb(const float* __restrict__ w,
                                                 u16* __restrict__ wbkt,
                                                 u16* __restrict__ wbv) {
  int idx = blockIdx.x * 256 + threadIdx.x;   // over 16*256*512
  int c = idx & 511;
  int rowh = idx >> 9;
  int h = rowh >> 8;
  int dr = rowh & 255;
  float v = w[idx];
  if (dr < NOPE) wbkt[((h * KVR + c) << 7) + dr] = f2b(v);           // (NH,512,128)
  else           wbv[((h * VH + (dr - NOPE)) << 9) + c] = f2b(v);    // (NH,128,512)
}

// ---------------- RMSNorm over 1024 (q path) ----------------
__global__ __launch_bounds__(256) void rms_q_kernel(const float* __restrict__ X,
                                                    const float* __restrict__ w,
                                                    u16* __restrict__ out) {
  int r = blockIdx.x, tid = threadIdx.x;
  const float4 v = *(const float4*)&X[(long)r * QR + tid * 4];
  float ss = v.x * v.x + v.y * v.y + v.z * v.z + v.w * v.w;
  for (int m = 1; m < 64; m <<= 1) ss += __shfl_xor(ss, m);
  __shared__ float red[4];
  if ((tid & 63) == 0) red[tid >> 6] = ss;
  __syncthreads();
  float tot = red[0] + red[1] + red[2] + red[3];
  float sc = rsqrtf(tot / QR + EPS_);
  float4 wv = *(const float4*)&w[tid * 4];
  uint2 o;
  o.x = pk2(v.x * sc * wv.x, v.y * sc * wv.y);
  o.y = pk2(v.z * sc * wv.z, v.w * sc * wv.w);
  *(uint2*)&out[(long)r * QR + tid * 4] = o;
}

// ---------------- q post (bf16 input): split nope / rope(pe), head-major ----------------
__global__ __launch_bounds__(256) void post_q_kernel(const u16* __restrict__ C2,
                                                     const float* __restrict__ fc,
                                                     const float* __restrict__ fs,
                                                     u16* __restrict__ qn,
                                                     u16* __restrict__ qp) {
  int r = blockIdx.x, tid = threadIdx.x;
  int s = r & (SS - 1);
  const u16* row = C2 + (long)r * (NH * QKH);
  for (int j = tid; j < NH * QKH / 2; j += 256) {
    int col = j * 2;
    int h = col / QKH;
    int dd = col - h * QKH;
    u32 pair = *(const u32*)&row[col];
    if (dd < NOPE) {
      *(u32*)&qn[((long)h * NTOK + r) * NOPE + dd] = pair;   // already bf16
    } else {
      float x0 = b2f(pair & 0xffffu), x1 = b2f(pair >> 16);
      int jr = (dd - NOPE) >> 1;
      float c = fc[s * 32 + jr], sn = fs[s * 32 + jr];
      *(u32*)&qp[((long)h * NTOK + r) * ROPE + (dd - NOPE)] =
          pk2(x0 * c - x1 * sn, x0 * sn + x1 * c);
    }
  }
}

// ---------------- kv post: rmsnorm(512) -> kv_sw (XOR-swizzled) + kv^T, rope k_pe_sw ----------------
// Swizzle: element index d' = d ^ ((t&7)<<3)  (== byte XOR ((t&7)<<4)) within each row.
__global__ __launch_bounds__(256) void post_kv_kernel(const float* __restrict__ C3,
                                                      const float* __restrict__ w,
                                                      const float* __restrict__ fc,
                                                      const float* __restrict__ fs,
                                                      u16* __restrict__ kv_sw,
                                                      u16* __restrict__ kvt,
                                                      u16* __restrict__ kpe_sw) {
  int r = blockIdx.x, tid = threadIdx.x;
  int b = r >> 10, t = r & (SS - 1);
  const float* row = C3 + (long)r * 576;
  float2 v = *(const float2*)&row[tid * 2];
  float ss = v.x * v.x + v.y * v.y;
  for (int m = 1; m < 64; m <<= 1) ss += __shfl_xor(ss, m);
  __shared__ float red[4];
  if ((tid & 63) == 0) red[tid >> 6] = ss;
  __syncthreads();
  float tot = red[0] + red[1] + red[2] + red[3];
  float sc = rsqrtf(tot / KVR + EPS_);
  int c = tid * 2;
  int xm = (t & 7) << 3;
  float y0 = v.x * sc * w[c], y1 = v.y * sc * w[c + 1];
  *(u32*)&kv_sw[((long)b * SS + t) * KVR + (c ^ xm)] = pk2(y0, y1);
  kvt[((long)b * KVR + c) * SS + t] = f2b(y0);
  kvt[((long)b * KVR + c + 1) * SS + t] = f2b(y1);
  if (tid < 32) {
    float x0 = row[KVR + tid * 2], x1 = row[KVR + tid * 2 + 1];
    float cc = fc[t * 32 + tid], sn = fs[t * 32 + tid];
    *(u32*)&kpe_sw[((long)b * SS + t) * ROPE + ((tid * 2) ^ xm)] =
        pk2(x0 * cc - x1 * sn, x0 * sn + x1 * cc);
  }
}

// ---------------- GEMM: C(M,N) = A(M,K) * B(N,K)^T, bf16 in, f32/bf16 out ----------------
template <bool CBF16>
__global__ __launch_bounds__(256) void gemm_bt(const u16* __restrict__ Ag,
                                               const u16* __restrict__ Bg,
                                               void* __restrict__ Cg,
                                               int M, int N, int K,
                                               int lda, int ldb, int ldc,
                                               long sA, long sB, long sC) {
  const u16* A = Ag + (long)blockIdx.z * sA;
  const u16* Bm = Bg + (long)blockIdx.z * sB;
  const int row0 = blockIdx.y * 128;
  const int col0 = blockIdx.x * 128;
  const int tid = threadIdx.x;
  const int wave = tid >> 6, lane = tid & 63;
  const int g = lane >> 4, r = lane & 15;
  const int wr = wave >> 1, wc = wave & 1;

  __shared__ u16 As[2][128 * 32];
  __shared__ u16 Bs[2][128 * 32];

  f32x4 acc[4][4] = {};
  const int nk = K >> 5;

  auto stage = [&](int kt, int p) {
    int k0 = kt << 5;
#pragma unroll
    for (int j = 0; j < 2; ++j) {
      int ldsoff = (j * 4096 + wave * 1024) >> 1;
      int rowi = j * 64 + wave * 16 + (lane >> 2);
      int coli = (lane & 3) << 3;
      const u16* ga = A + (long)(row0 + rowi) * lda + k0 + coli;
      __builtin_amdgcn_global_load_lds(
          (const __attribute__((address_space(1))) void*)ga,
          (__attribute__((address_space(3))) void*)(&As[p][ldsoff]), 16, 0, 0);
      int rb = col0 + rowi; if (rb > N - 1) rb = N - 1;
      const u16* gb = Bm + (long)rb * ldb + k0 + coli;
      __builtin_amdgcn_global_load_lds(
          (const __attribute__((address_space(1))) void*)gb,
          (__attribute__((address_space(3))) void*)(&Bs[p][ldsoff]), 16, 0, 0);
    }
  };

  stage(0, 0);
  for (int kt = 0; kt < nk; ++kt) {
    __syncthreads();
    if (kt + 1 < nk) stage(kt + 1, (kt + 1) & 1);
    const int p = kt & 1;
    bf16x8 af[4], bf[4];
#pragma unroll
    for (int i = 0; i < 4; i++) {
      af[i] = *(const bf16x8*)&As[p][(wr * 64 + i * 16 + r) * 32 + g * 8];
      bf[i] = *(const bf16x8*)&Bs[p][(wc * 64 + i * 16 + r) * 32 + g * 8];
    }
#pragma unroll
    for (int i = 0; i < 4; i++)
#pragma unroll
      for (int j = 0; j < 4; j++)
        acc[i][j] = MFMA16(af[i], bf[j], acc[i][j], 0, 0, 0);
  }

#pragma unroll
  for (int i = 0; i < 4; i++)
#pragma unroll
    for (int j = 0; j < 4; j++) {
      int rowb = row0 + wr * 64 + i * 16 + g * 4;
      int colc = col0 + wc * 64 + j * 16 + r;
      if (colc < N) {
        if constexpr (CBF16) {
          u16* C = (u16*)Cg + (long)blockIdx.z * sC;
#pragma unroll
          for (int e = 0; e < 4; e++)
            C[(long)(rowb + e) * ldc + colc] = f2b(acc[i][j][e]);
        } else {
          float* C = (float*)Cg + (long)blockIdx.z * sC;
#pragma unroll
          for (int e = 0; e < 4; e++)
            C[(long)(rowb + e) * ldc + colc] = acc[i][j][e];
        }
      }
    }
}

// ---------------- flash attention v2: 8-wave cooperative, 64 q-rows/block ----------------
// QK: wave = (rc 0..3, dh 0..1): rows rc*16, keys all 32, d-half dh. Partial scores
// exchanged via LDS. PV: wave = (wr 0..1, wc 0..3): rows wr*32, v-cols wc*128.
__global__ __launch_bounds__(512, 2) void attn_kernel(
    const u16* __restrict__ q_lat, const u16* __restrict__ q_pe,
    const u16* __restrict__ kv_sw, const u16* __restrict__ kvt,
    const u16* __restrict__ kpe_sw, u16* __restrict__ o_lat) {
  const int h = blockIdx.y, b = blockIdx.z;
  const int qb = ((int)gridDim.x - 1 - (int)blockIdx.x) * 64;   // heavy blocks first
  const int wave = threadIdx.x >> 6, lane = threadIdx.x & 63;
  const int g = lane >> 4, r = lane & 15;
  const int rc = wave >> 1, dh = wave & 1;        // QK roles
  const int wr = wave >> 2, wc = wave & 3;        // PV roles

  __shared__ __attribute__((aligned(16))) u16 Ks[32 * 512];      // 32 KB swizzled K tile
  __shared__ __attribute__((aligned(16))) u16 Kp[32 * 64];       // 4 KB swizzled Kpe tile
  __shared__ __attribute__((aligned(16))) u16 P[64][40];         // 5 KB
  __shared__ __attribute__((aligned(16))) float Sb[4][2][16][36]; // 18 KB partial scores
  __shared__ __attribute__((aligned(16))) float alphab[64];
  __shared__ __attribute__((aligned(16))) float lbuf[64];

  const u16* Q  = q_lat + ((long)h * NTOK + (long)b * SS + qb + rc * 16 + r) * KVR;
  const u16* Qp = q_pe  + ((long)h * NTOK + (long)b * SS + qb + rc * 16 + r) * ROPE;
  const u16* KVg = kv_sw + (long)b * SS * KVR;
  const u16* KPg = kpe_sw + (long)b * SS * ROPE;
  const u16* KT  = kvt + (long)b * KVR * SS;

  f32x4 acc[2][8];
#pragma unroll
  for (int i = 0; i < 2; i++)
#pragma unroll
    for (int j = 0; j < 8; j++) acc[i][j] = f32x4{0.f, 0.f, 0.f, 0.f};

  float m_run = -1e30f, l_run = 0.f;
  const int q_row = qb + rc * 16 + r;
  const int nt = (qb + 95) >> 5;
  const int xm = (r & 7) << 3;     // element-space XOR mask (rows 16+r share r&7)

  auto stage = [&](int t0) {
#pragma unroll
    for (int i = 0; i < 4; ++i) {
      int row = wave * 4 + i;
      const u16* ga = KVg + (long)(t0 + row) * KVR + lane * 8;
      __builtin_amdgcn_global_load_lds(
          (const __attribute__((address_space(1))) void*)ga,
          (__attribute__((address_space(3))) void*)(&Ks[row * 512]), 16, 0, 0);
    }
    if (wave < 4) {   // 4 issues cover 32 rows x 64 (rows contiguous)
      const u16* ga = KPg + (long)(t0 + wave * 8) * ROPE + lane * 8;
      __builtin_amdgcn_global_load_lds(
          (const __attribute__((address_space(1))) void*)ga,
          (__attribute__((address_space(3))) void*)(&Kp[wave * 8 * 64]), 16, 0, 0);
    }
  };

  stage(0);
  __syncthreads();

  for (int tt = 0; tt < nt; ++tt) {
    const int t0 = tt * 32;
    f32x4 st0 = {0.f, 0.f, 0.f, 0.f}, st1 = {0.f, 0.f, 0.f, 0.f};
    if (dh == 0) {
#pragma unroll
      for (int c = 0; c < 9; ++c) {
        int d0 = c * 32;
        bf16x8 qf = *(const bf16x8*)&Q[d0 + g * 8];
        int ix = (d0 + g * 8) ^ xm;
        bf16x8 k0 = *(const bf16x8*)&Ks[r * 512 + ix];
        bf16x8 k1 = *(const bf16x8*)&Ks[(16 + r) * 512 + ix];
        st0 = MFMA16(k0, qf, st0, 0, 0, 0);
        st1 = MFMA16(k1, qf, st1, 0, 0, 0);
      }
    } else {
#pragma unroll
      for (int c = 0; c < 7; ++c) {
        int d0 = 288 + c * 32;
        bf16x8 qf = *(const bf16x8*)&Q[d0 + g * 8];
        int ix = (d0 + g * 8) ^ xm;
        bf16x8 k0 = *(const bf16x8*)&Ks[r * 512 + ix];
        bf16x8 k1 = *(const bf16x8*)&Ks[(16 + r) * 512 + ix];
        st0 = MFMA16(k0, qf, st0, 0, 0, 0);
        st1 = MFMA16(k1, qf, st1, 0, 0, 0);
      }
#pragma unroll
      for (int c = 0; c < 2; ++c) {
        int d0 = c * 32;
        bf16x8 qf = *(const bf16x8*)&Qp[d0 + g * 8];
        int ix = (d0 + g * 8) ^ xm;
        bf16x8 k0 = *(const bf16x8*)&Kp[r * 64 + ix];
        bf16x8 k1 = *(const bf16x8*)&Kp[(16 + r) * 64 + ix];
        st0 = MFMA16(k0, qf, st0, 0, 0, 0);
        st1 = MFMA16(k1, qf, st1, 0, 0, 0);
      }
    }
    // exchange partial scores
    *(f32x4*)&Sb[rc][dh][r][g * 4] = st0;
    *(f32x4*)&Sb[rc][dh][r][16 + g * 4] = st1;
    __syncthreads();                       // B2: K-tile reads retired too
    if (tt + 1 < nt) stage(t0 + 32);       // prefetch next K tile (visible by B3)
    st0 += *(const f32x4*)&Sb[rc][1 - dh][r][g * 4];
    st1 += *(const f32x4*)&Sb[rc][1 - dh][r][16 + g * 4];

    // wave-local softmax over full 32-key tile (lane has keys {g*4+i, 16+g*4+i})
    float sv[8];
    float smax = -1e30f;
#pragma unroll
    for (int i = 0; i < 4; i++) {
      int t = t0 + g * 4 + i;
      sv[i]     = (t      <= q_row) ? st0[i] * SCALE_ : -1e30f;
      sv[4 + i] = (t + 16 <= q_row) ? st1[i] * SCALE_ : -1e30f;
      smax = fmaxf(smax, fmaxf(sv[i], sv[4 + i]));
    }
    smax = fmaxf(smax, __shfl_xor(smax, 16));
    smax = fmaxf(smax, __shfl_xor(smax, 32));
    float m_new = fmaxf(m_run, smax);
    float alpha = __expf(m_run - m_new);
    float p[8], ps = 0.f;
#pragma unroll
    for (int i = 0; i < 8; i++) {
      p[i] = (sv[i] < -1e29f) ? 0.f : __expf(sv[i] - m_new);
      ps += p[i];
    }
    ps += __shfl_xor(ps, 16);
    ps += __shfl_xor(ps, 32);
    l_run = l_run * alpha + ps;
    m_run = m_new;
    // write P half owned by this dh
    uint2 pw;
    pw.x = pk2(p[dh * 4 + 0], p[dh * 4 + 1]);
    pw.y = pk2(p[dh * 4 + 2], p[dh * 4 + 3]);
    *(uint2*)&P[rc * 16 + r][dh * 16 + g * 4] = pw;
    if (dh == 0 && g == 0) alphab[rc * 16 + r] = alpha;
    __syncthreads();                       // B3
    // ---- PV ----
    f32x4 a4_0 = *(const f32x4*)&alphab[wr * 32 + g * 4];
    f32x4 a4_1 = *(const f32x4*)&alphab[wr * 32 + 16 + g * 4];
    bf16x8 pa0 = *(const bf16x8*)&P[wr * 32 + r][g * 8];
    bf16x8 pa1 = *(const bf16x8*)&P[wr * 32 + 16 + r][g * 8];
#pragma unroll
    for (int cf = 0; cf < 8; ++cf) {
      bf16x8 vf = *(const bf16x8*)&KT[(long)(wc * 128 + cf * 16 + r) * SS + t0 + g * 8];
      acc[0][cf] = MFMA16(pa0, vf, acc[0][cf] * a4_0, 0, 0, 0);
      acc[1][cf] = MFMA16(pa1, vf, acc[1][cf] * a4_1, 0, 0, 0);
    }
  }

  if (dh == 0 && g == 0) lbuf[rc * 16 + r] = l_run;
  __syncthreads();
  f32x4 li0 = *(const f32x4*)&lbuf[wr * 32 + g * 4];
  f32x4 li1 = *(const f32x4*)&lbuf[wr * 32 + 16 + g * 4];
#pragma unroll
  for (int e = 0; e < 4; e++) { li0[e] = 1.f / li0[e]; li1[e] = 1.f / li1[e]; }
  u16* O = o_lat + ((long)h * NTOK + (long)b * SS + qb) * KVR;
#pragma unroll
  for (int cf = 0; cf < 8; ++cf) {
    int col = wc * 128 + cf * 16 + r;
#pragma unroll
    for (int e = 0; e < 4; e++) {
      O[(long)(wr * 32 + g * 4 + e) * KVR + col]      = f2b(acc[0][cf][e] * li0[e]);
      O[(long)(wr * 32 + 16 + g * 4 + e) * KVR + col] = f2b(acc[1][cf][e] * li1[e]);
    }
  }
}

// ---------------- host launch ----------------
extern "C" void kernel_launch(void* const* d_in, const int* in_sizes, int n_in,
                              void* d_out, int out_size, void* d_ws, size_t ws_size,
                              hipStream_t stream) {
  (void)in_sizes; (void)n_in; (void)out_size; (void)ws_size;
  const float* x    = (const float*)d_in[0];
  const float* fc   = (const float*)d_in[2];
  const float* fs   = (const float*)d_in[3];
  const float* wqa  = (const float*)d_in[4];
  const float* qnw  = (const float*)d_in[5];
  const float* wqb  = (const float*)d_in[6];
  const float* wkva = (const float*)d_in[7];
  const float* kvnw = (const float*)d_in[8];
  const float* wkvb = (const float*)d_in[9];
  const float* wo   = (const float*)d_in[10];
  float* out = (float*)d_out;

  char* w = (char*)d_ws;
  size_t off = 0;
  auto alloc = [&](size_t bytes) {
    void* p = w + off;
    off += (bytes + 255) & ~(size_t)255;
    return p;
  };
  // ---- persistent region ----
  u16* wbkt   = (u16*)alloc((size_t)NH * KVR * NOPE * 2);
  u16* wbv    = (u16*)alloc((size_t)NH * VH * KVR * 2);
  u16* wo_b   = (u16*)alloc((size_t)DIM * DIM * 2);
  u16* qnope  = (u16*)alloc((size_t)NH * NTOK * NOPE * 2);
  u16* qpe    = (u16*)alloc((size_t)NH * NTOK * ROPE * 2);
  u16* kv_sw  = (u16*)alloc((size_t)BB * SS * KVR * 2);
  u16* kvt    = (u16*)alloc((size_t)BB * KVR * SS * 2);
  u16* kpe_sw = (u16*)alloc((size_t)BB * SS * ROPE * 2);
  u16* oflat  = (u16*)alloc((size_t)NTOK * DIM * 2);
  // ---- transient region, later overlaid by qlat/olat ----
  u16* qlat   = (u16*)(w + off);            // overlay base
  u16* olat   = qlat;                       // attention writes O in-place over Q
  u16* x_bf   = (u16*)alloc((size_t)NTOK * DIM * 2);
  u16* wqa_b  = (u16*)alloc((size_t)QR * DIM * 2);
  u16* wqb_b  = (u16*)alloc((size_t)NH * QKH * QR * 2);
  u16* wkva_b = (u16*)alloc((size_t)576 * DIM * 2);
  u16* qn     = (u16*)alloc((size_t)NTOK * QR * 2);
  float* C1   = (float*)alloc((size_t)NTOK * QR * 4);
  u16* C2b    = (u16*)alloc((size_t)NTOK * NH * QKH * 2);

  cvt_bf16<<<(NTOK * DIM) / 2048, 256, 0, stream>>>(x, x_bf, NTOK * DIM);
  cvt_bf16<<<(QR * DIM) / 2048, 256, 0, stream>>>(wqa, wqa_b, QR * DIM);
  cvt_bf16<<<(NH * QKH * QR) / 2048, 256, 0, stream>>>(wqb, wqb_b, NH * QKH * QR);
  cvt_bf16<<<(576 * DIM) / 2048, 256, 0, stream>>>(wkva, wkva_b, 576 * DIM);
  cvt_bf16<<<(DIM * DIM) / 2048, 256, 0, stream>>>(wo, wo_b, DIM * DIM);
  prep_wkvb<<<(NH * 256 * KVR) / 256, 256, 0, stream>>>(wkvb, wbkt, wbv);

  gemm_bt<false><<<dim3(QR / 128, NTOK / 128, 1), 256, 0, stream>>>(
      x_bf, wqa_b, C1, NTOK, QR, DIM, DIM, DIM, QR, 0, 0, 0);
  rms_q_kernel<<<NTOK, 256, 0, stream>>>(C1, qnw, qn);
  gemm_bt<true><<<dim3(NH * QKH / 128, NTOK / 128, 1), 256, 0, stream>>>(
      qn, wqb_b, C2b, NTOK, NH * QKH, QR, QR, QR, NH * QKH, 0, 0, 0);
  post_q_kernel<<<NTOK, 256, 0, stream>>>(C2b, fc, fs, qnope, qpe);
  gemm_bt<false><<<dim3(5, NTOK / 128, 1), 256, 0, stream>>>(
      x_bf, wkva_b, C1, NTOK, 576, DIM, DIM, DIM, 576, 0, 0, 0);
  post_kv_kernel<<<NTOK, 256, 0, stream>>>(C1, kvnw, fc, fs, kv_sw, kvt, kpe_sw);
  gemm_bt<true><<<dim3(KVR / 128, NTOK / 128, NH), 256, 0, stream>>>(
      qnope, wbkt, qlat, NTOK, KVR, NOPE, NOPE, NOPE, KVR,
      (long)NTOK * NOPE, (long)KVR * NOPE, (long)NTOK * KVR);
  attn_kernel<<<dim3(SS / 64, NH, BB), 512, 0, stream>>>(
      qlat, qpe, kv_sw, kvt, kpe_sw, olat);
  gemm_bt<true><<<dim3(1, NTOK / 128, NH), 256, 0, stream>>>(
      olat, wbv, oflat, NTOK, VH, KVR, KVR, KVR, DIM,
      (long)NTOK * KVR, (long)VH * KVR, (long)VH);
  gemm_bt<false><<<dim3(DIM / 128, NTOK / 128, 1), 256, 0, stream>>>(
      oflat, wo_b, out, NTOK, DIM, DIM, DIM, DIM, DIM, 0, 0, 0);
}

// Round 4
// 538.559 us; speedup vs baseline: 3.2883x; 1.7796x over previous
//
#include <hip/hip_runtime.h>
#include <hip/hip_bf16.h>
#include <stdint.h>

#define BB 4
#define SS 1024
#define DIM 2048
#define NH 16
#define QR 1024
#define KVR 512
#define NOPE 128
#define ROPE 64
#define VH 128
#define QKH 192
#define NTOK 4096

static constexpr float SCALE_ = 0.07216878364870322f; // 192^-0.5
static constexpr float EPS_ = 1e-6f;

typedef unsigned short u16;
typedef unsigned int u32;
using f32x4  = __attribute__((ext_vector_type(4))) float;
using bf16x8 = __attribute__((ext_vector_type(8))) __bf16;

#define MFMA16 __builtin_amdgcn_mfma_f32_16x16x32_bf16

__device__ __forceinline__ u16 f2b(float f) {
  u32 u = __float_as_uint(f);
  u32 r = u + 0x7fffu + ((u >> 16) & 1u);   // RNE
  return (u16)(r >> 16);
}
__device__ __forceinline__ u32 pk2(float a, float b) {
  return (u32)f2b(a) | ((u32)f2b(b) << 16);
}
__device__ __forceinline__ float b2f(u32 hi16) {
  return __uint_as_float(hi16 << 16);
}

// ---------------- f32 -> bf16 convert (8 elems/thread) ----------------
__global__ __launch_bounds__(256) void cvt_bf16(const float* __restrict__ in,
                                                u16* __restrict__ out, int n) {
  int i = (blockIdx.x * 256 + threadIdx.x) * 8;
  if (i >= n) return;
  float4 a = *(const float4*)&in[i];
  float4 b = *(const float4*)&in[i + 4];
  uint4 o;
  o.x = pk2(a.x, a.y); o.y = pk2(a.z, a.w);
  o.z = pk2(b.x, b.y); o.w = pk2(b.z, b.w);
  *(uint4*)&out[i] = o;
}

// ---------------- wkv_b split: wb_k transposed per head, wb_v straight ----------------
__global__ __launch_bounds__(256) void prep_wkvb(const float* __restrict__ w,
                                                 u16* __restrict__ wbkt,
                                                 u16* __restrict__ wbv) {
  int idx = blockIdx.x * 256 + threadIdx.x;   // over 16*256*512
  int c = idx & 511;
  int rowh = idx >> 9;
  int h = rowh >> 8;
  int dr = rowh & 255;
  float v = w[idx];
  if (dr < NOPE) wbkt[((h * KVR + c) << 7) + dr] = f2b(v);           // (NH,512,128)
  else           wbv[((h * VH + (dr - NOPE)) << 9) + c] = f2b(v);    // (NH,128,512)
}

// ---------------- RMSNorm over 1024 (q path) ----------------
__global__ __launch_bounds__(256) void rms_q_kernel(const float* __restrict__ X,
                                                    const float* __restrict__ w,
                                                    u16* __restrict__ out) {
  int r = blockIdx.x, tid = threadIdx.x;
  const float4 v = *(const float4*)&X[(long)r * QR + tid * 4];
  float ss = v.x * v.x + v.y * v.y + v.z * v.z + v.w * v.w;
  for (int m = 1; m < 64; m <<= 1) ss += __shfl_xor(ss, m);
  __shared__ float red[4];
  if ((tid & 63) == 0) red[tid >> 6] = ss;
  __syncthreads();
  float tot = red[0] + red[1] + red[2] + red[3];
  float sc = rsqrtf(tot / QR + EPS_);
  float4 wv = *(const float4*)&w[tid * 4];
  uint2 o;
  o.x = pk2(v.x * sc * wv.x, v.y * sc * wv.y);
  o.y = pk2(v.z * sc * wv.z, v.w * sc * wv.w);
  *(uint2*)&out[(long)r * QR + tid * 4] = o;
}

// ---------------- q post (bf16 input): split nope / rope(pe), head-major ----------------
__global__ __launch_bounds__(256) void post_q_kernel(const u16* __restrict__ C2,
                                                     const float* __restrict__ fc,
                                                     const float* __restrict__ fs,
                                                     u16* __restrict__ qn,
                                                     u16* __restrict__ qp) {
  int r = blockIdx.x, tid = threadIdx.x;
  int s = r & (SS - 1);
  const u16* row = C2 + (long)r * (NH * QKH);
  for (int j = tid; j < NH * QKH / 2; j += 256) {
    int col = j * 2;
    int h = col / QKH;
    int dd = col - h * QKH;
    u32 pair = *(const u32*)&row[col];
    if (dd < NOPE) {
      *(u32*)&qn[((long)h * NTOK + r) * NOPE + dd] = pair;   // already bf16
    } else {
      float x0 = b2f(pair & 0xffffu), x1 = b2f(pair >> 16);
      int jr = (dd - NOPE) >> 1;
      float c = fc[s * 32 + jr], sn = fs[s * 32 + jr];
      *(u32*)&qp[((long)h * NTOK + r) * ROPE + (dd - NOPE)] =
          pk2(x0 * c - x1 * sn, x0 * sn + x1 * c);
    }
  }
}

// ---------------- kv post: rmsnorm(512) -> kv_sw (XOR-swizzled) + kv^T, rope k_pe_sw ----------------
// Swizzle: element index d' = d ^ ((t&7)<<3) within each row.
__global__ __launch_bounds__(256) void post_kv_kernel(const float* __restrict__ C3,
                                                      const float* __restrict__ w,
                                                      const float* __restrict__ fc,
                                                      const float* __restrict__ fs,
                                                      u16* __restrict__ kv_sw,
                                                      u16* __restrict__ kvt,
                                                      u16* __restrict__ kpe_sw) {
  int r = blockIdx.x, tid = threadIdx.x;
  int b = r >> 10, t = r & (SS - 1);
  const float* row = C3 + (long)r * 576;
  float2 v = *(const float2*)&row[tid * 2];
  float ss = v.x * v.x + v.y * v.y;
  for (int m = 1; m < 64; m <<= 1) ss += __shfl_xor(ss, m);
  __shared__ float red[4];
  if ((tid & 63) == 0) red[tid >> 6] = ss;
  __syncthreads();
  float tot = red[0] + red[1] + red[2] + red[3];
  float sc = rsqrtf(tot / KVR + EPS_);
  int c = tid * 2;
  int xm = (t & 7) << 3;
  float y0 = v.x * sc * w[c], y1 = v.y * sc * w[c + 1];
  *(u32*)&kv_sw[((long)b * SS + t) * KVR + (c ^ xm)] = pk2(y0, y1);
  kvt[((long)b * KVR + c) * SS + t] = f2b(y0);
  kvt[((long)b * KVR + c + 1) * SS + t] = f2b(y1);
  if (tid < 32) {
    float x0 = row[KVR + tid * 2], x1 = row[KVR + tid * 2 + 1];
    float cc = fc[t * 32 + tid], sn = fs[t * 32 + tid];
    *(u32*)&kpe_sw[((long)b * SS + t) * ROPE + ((tid * 2) ^ xm)] =
        pk2(x0 * cc - x1 * sn, x0 * sn + x1 * cc);
  }
}

// ---------------- GEMM: C(M,N) = A(M,K) * B(N,K)^T, bf16 in, f32/bf16 out ----------------
template <bool CBF16>
__global__ __launch_bounds__(256) void gemm_bt(const u16* __restrict__ Ag,
                                               const u16* __restrict__ Bg,
                                               void* __restrict__ Cg,
                                               int M, int N, int K,
                                               int lda, int ldb, int ldc,
                                               long sA, long sB, long sC) {
  const u16* A = Ag + (long)blockIdx.z * sA;
  const u16* Bm = Bg + (long)blockIdx.z * sB;
  const int row0 = blockIdx.y * 128;
  const int col0 = blockIdx.x * 128;
  const int tid = threadIdx.x;
  const int wave = tid >> 6, lane = tid & 63;
  const int g = lane >> 4, r = lane & 15;
  const int wr = wave >> 1, wc = wave & 1;

  __shared__ u16 As[2][128 * 32];
  __shared__ u16 Bs[2][128 * 32];

  f32x4 acc[4][4] = {};
  const int nk = K >> 5;

  auto stage = [&](int kt, int p) {
    int k0 = kt << 5;
#pragma unroll
    for (int j = 0; j < 2; ++j) {
      int ldsoff = (j * 4096 + wave * 1024) >> 1;
      int rowi = j * 64 + wave * 16 + (lane >> 2);
      int coli = (lane & 3) << 3;
      const u16* ga = A + (long)(row0 + rowi) * lda + k0 + coli;
      __builtin_amdgcn_global_load_lds(
          (const __attribute__((address_space(1))) void*)ga,
          (__attribute__((address_space(3))) void*)(&As[p][ldsoff]), 16, 0, 0);
      int rb = col0 + rowi; if (rb > N - 1) rb = N - 1;
      const u16* gb = Bm + (long)rb * ldb + k0 + coli;
      __builtin_amdgcn_global_load_lds(
          (const __attribute__((address_space(1))) void*)gb,
          (__attribute__((address_space(3))) void*)(&Bs[p][ldsoff]), 16, 0, 0);
    }
  };

  stage(0, 0);
  for (int kt = 0; kt < nk; ++kt) {
    __syncthreads();
    if (kt + 1 < nk) stage(kt + 1, (kt + 1) & 1);
    const int p = kt & 1;
    bf16x8 af[4], bf[4];
#pragma unroll
    for (int i = 0; i < 4; i++) {
      af[i] = *(const bf16x8*)&As[p][(wr * 64 + i * 16 + r) * 32 + g * 8];
      bf[i] = *(const bf16x8*)&Bs[p][(wc * 64 + i * 16 + r) * 32 + g * 8];
    }
#pragma unroll
    for (int i = 0; i < 4; i++)
#pragma unroll
      for (int j = 0; j < 4; j++)
        acc[i][j] = MFMA16(af[i], bf[j], acc[i][j], 0, 0, 0);
  }

#pragma unroll
  for (int i = 0; i < 4; i++)
#pragma unroll
    for (int j = 0; j < 4; j++) {
      int rowb = row0 + wr * 64 + i * 16 + g * 4;
      int colc = col0 + wc * 64 + j * 16 + r;
      if (colc < N) {
        if constexpr (CBF16) {
          u16* C = (u16*)Cg + (long)blockIdx.z * sC;
#pragma unroll
          for (int e = 0; e < 4; e++)
            C[(long)(rowb + e) * ldc + colc] = f2b(acc[i][j][e]);
        } else {
          float* C = (float*)Cg + (long)blockIdx.z * sC;
#pragma unroll
          for (int e = 0; e < 4; e++)
            C[(long)(rowb + e) * ldc + colc] = acc[i][j][e];
        }
      }
    }
}

// ---------------- flash attention v3 ----------------
// 8 waves/block. Each wave owns 16 q-rows for QK+softmax (full 576-dim, Q in regs).
// PV: P shared via LDS; each wave computes all 128 rows x its own 64 V-cols.
// Block processes chunk pair (j, 7-j) of 128 rows => equal work (36 tiles) per block.
// Batch pinned to XCD pair via bid&7 decode => KV L2-resident per XCD.
__global__ __launch_bounds__(512) void attn_kernel(
    const u16* __restrict__ q_lat, const u16* __restrict__ q_pe,
    const u16* __restrict__ kv_sw, const u16* __restrict__ kvt,
    const u16* __restrict__ kpe_sw, u16* __restrict__ o_lat) {
  const int bid = blockIdx.x;
  const int xcd = bid & 7, idx = bid >> 3;
  const int b = xcd >> 1;
  const int h = idx & 15;
  const int jp = ((xcd & 1) << 1) | (idx >> 4);   // 0..3
  const int wv = threadIdx.x >> 6, lane = threadIdx.x & 63;
  const int g = lane >> 4, r = lane & 15;
  const int xm = (r & 7) << 3;

  __shared__ __attribute__((aligned(16))) u16 Ks[32 * 512];   // 32 KB (swizzled rows)
  __shared__ __attribute__((aligned(16))) u16 P[128][40];     // 10 KB padded
  __shared__ __attribute__((aligned(16))) float alphab[128];
  __shared__ __attribute__((aligned(16))) float lbuf[128];

  const u16* KVg = kv_sw + (long)b * SS * KVR;
  const u16* KPg = kpe_sw + (long)b * SS * ROPE;
  const u16* KT  = kvt + (long)b * KVR * SS;

  auto stage = [&](int t0) {
#pragma unroll
    for (int i = 0; i < 4; ++i) {
      int row = wv * 4 + i;
      const u16* ga = KVg + (long)(t0 + row) * KVR + lane * 8;
      __builtin_amdgcn_global_load_lds(
          (const __attribute__((address_space(1))) void*)ga,
          (__attribute__((address_space(3))) void*)(&Ks[row * 512]), 16, 0, 0);
    }
  };

  for (int seg = 0; seg < 2; ++seg) {
    const int jc = seg ? (7 - jp) : jp;
    const int qa = jc * 128;
    const int nt = (qa >> 5) + 4;          // tiles of 32 keys
    const int q_row = qa + wv * 16 + r;

    const u16* Q  = q_lat + ((long)h * NTOK + (long)b * SS + q_row) * KVR;
    const u16* Qp = q_pe  + ((long)h * NTOK + (long)b * SS + q_row) * ROPE;
    bf16x8 qf[16], qp[2];
#pragma unroll
    for (int c = 0; c < 16; ++c) qf[c] = *(const bf16x8*)&Q[c * 32 + g * 8];
    qp[0] = *(const bf16x8*)&Qp[g * 8];
    qp[1] = *(const bf16x8*)&Qp[32 + g * 8];

    f32x4 acc[8][4];
#pragma unroll
    for (int i = 0; i < 8; i++)
#pragma unroll
      for (int j = 0; j < 4; j++) acc[i][j] = f32x4{0.f, 0.f, 0.f, 0.f};
    float m_run = -1e30f, l_run = 0.f;

    stage(0);
    __syncthreads();

    for (int tt = 0; tt < nt; ++tt) {
      const int t0 = tt << 5;
      // V prefetch (consumed after B1; drained there)
      bf16x8 vf[4];
#pragma unroll
      for (int nc = 0; nc < 4; ++nc)
        vf[nc] = *(const bf16x8*)&KT[(long)(wv * 64 + nc * 16 + r) * SS + t0 + g * 8];

      // QK^T (full 576 per wave)
      f32x4 st0 = {0.f, 0.f, 0.f, 0.f}, st1 = {0.f, 0.f, 0.f, 0.f};
#pragma unroll
      for (int c = 0; c < 16; ++c) {
        int ix = (c * 32 + g * 8) ^ xm;
        bf16x8 k0 = *(const bf16x8*)&Ks[r * 512 + ix];
        bf16x8 k1 = *(const bf16x8*)&Ks[(16 + r) * 512 + ix];
        st0 = MFMA16(k0, qf[c], st0, 0, 0, 0);
        st1 = MFMA16(k1, qf[c], st1, 0, 0, 0);
      }
#pragma unroll
      for (int c = 0; c < 2; ++c) {
        int ix = (c * 32 + g * 8) ^ xm;
        bf16x8 k0 = *(const bf16x8*)&KPg[(long)(t0 + r) * ROPE + ix];
        bf16x8 k1 = *(const bf16x8*)&KPg[(long)(t0 + 16 + r) * ROPE + ix];
        st0 = MFMA16(k0, qp[c], st0, 0, 0, 0);
        st1 = MFMA16(k1, qp[c], st1, 0, 0, 0);
      }

      // softmax (lane owns q-row q_row; keys {t0+g*4+i, t0+16+g*4+i})
      float sv[8];
      float smax = -1e30f;
#pragma unroll
      for (int i = 0; i < 4; i++) {
        int t = t0 + g * 4 + i;
        sv[i]     = (t      <= q_row) ? st0[i] * SCALE_ : -1e30f;
        sv[4 + i] = (t + 16 <= q_row) ? st1[i] * SCALE_ : -1e30f;
        smax = fmaxf(smax, fmaxf(sv[i], sv[4 + i]));
      }
      smax = fmaxf(smax, __shfl_xor(smax, 16));
      smax = fmaxf(smax, __shfl_xor(smax, 32));
      float m_new = fmaxf(m_run, smax);
      float alpha = __expf(m_run - m_new);
      float p[8], ps = 0.f;
#pragma unroll
      for (int i = 0; i < 8; i++) {
        p[i] = (sv[i] < -1e29f) ? 0.f : __expf(sv[i] - m_new);
        ps += p[i];
      }
      ps += __shfl_xor(ps, 16);
      ps += __shfl_xor(ps, 32);
      l_run = l_run * alpha + ps;
      m_run = m_new;

      uint2 pw0, pw1;
      pw0.x = pk2(p[0], p[1]); pw0.y = pk2(p[2], p[3]);
      pw1.x = pk2(p[4], p[5]); pw1.y = pk2(p[6], p[7]);
      *(uint2*)&P[wv * 16 + r][g * 4]      = pw0;
      *(uint2*)&P[wv * 16 + r][16 + g * 4] = pw1;
      if (g == 0) alphab[wv * 16 + r] = alpha;
      __syncthreads();                     // B1: P/alpha visible; Ks reads retired
      if (tt + 1 < nt) stage(t0 + 32);     // overwrite Ks; drained at B2

      // PV: all 128 rows x own 64 cols
#pragma unroll
      for (int mc = 0; mc < 8; ++mc) {
        bf16x8 pa = *(const bf16x8*)&P[mc * 16 + r][g * 8];
        f32x4 a4 = *(const f32x4*)&alphab[mc * 16 + g * 4];
#pragma unroll
        for (int nc = 0; nc < 4; ++nc) {
          f32x4 t = acc[mc][nc] * a4;
          acc[mc][nc] = MFMA16(pa, vf[nc], t, 0, 0, 0);
        }
      }
      __syncthreads();                     // B2: stage drained; P safe to rewrite
    }

    if (g == 0) lbuf[wv * 16 + r] = l_run;
    __syncthreads();
    u16* O = o_lat + ((long)h * NTOK + (long)b * SS + qa) * KVR;
#pragma unroll
    for (int mc = 0; mc < 8; ++mc) {
      f32x4 li = *(const f32x4*)&lbuf[mc * 16 + g * 4];
#pragma unroll
      for (int e = 0; e < 4; e++) li[e] = 1.f / li[e];
#pragma unroll
      for (int nc = 0; nc < 4; ++nc) {
        int col = wv * 64 + nc * 16 + r;
#pragma unroll
        for (int e = 0; e < 4; e++)
          O[(long)(mc * 16 + g * 4 + e) * KVR + col] = f2b(acc[mc][nc][e] * li[e]);
      }
    }
    __syncthreads();                       // lbuf/Ks safe for next seg
  }
}

// ---------------- host launch ----------------
extern "C" void kernel_launch(void* const* d_in, const int* in_sizes, int n_in,
                              void* d_out, int out_size, void* d_ws, size_t ws_size,
                              hipStream_t stream) {
  (void)in_sizes; (void)n_in; (void)out_size; (void)ws_size;
  const float* x    = (const float*)d_in[0];
  const float* fc   = (const float*)d_in[2];
  const float* fs   = (const float*)d_in[3];
  const float* wqa  = (const float*)d_in[4];
  const float* qnw  = (const float*)d_in[5];
  const float* wqb  = (const float*)d_in[6];
  const float* wkva = (const float*)d_in[7];
  const float* kvnw = (const float*)d_in[8];
  const float* wkvb = (const float*)d_in[9];
  const float* wo   = (const float*)d_in[10];
  float* out = (float*)d_out;

  char* w = (char*)d_ws;
  size_t off = 0;
  auto alloc = [&](size_t bytes) {
    void* p = w + off;
    off += (bytes + 255) & ~(size_t)255;
    return p;
  };
  // ---- persistent region ----
  u16* wbkt   = (u16*)alloc((size_t)NH * KVR * NOPE * 2);
  u16* wbv    = (u16*)alloc((size_t)NH * VH * KVR * 2);
  u16* wo_b   = (u16*)alloc((size_t)DIM * DIM * 2);
  u16* qnope  = (u16*)alloc((size_t)NH * NTOK * NOPE * 2);
  u16* qpe    = (u16*)alloc((size_t)NH * NTOK * ROPE * 2);
  u16* kv_sw  = (u16*)alloc((size_t)BB * SS * KVR * 2);
  u16* kvt    = (u16*)alloc((size_t)BB * KVR * SS * 2);
  u16* kpe_sw = (u16*)alloc((size_t)BB * SS * ROPE * 2);
  u16* oflat  = (u16*)alloc((size_t)NTOK * DIM * 2);
  // ---- transient region, later overlaid by qlat/olat ----
  u16* qlat   = (u16*)(w + off);            // overlay base
  u16* olat   = qlat;                       // attention writes O in-place over Q
  u16* x_bf   = (u16*)alloc((size_t)NTOK * DIM * 2);
  u16* wqa_b  = (u16*)alloc((size_t)QR * DIM * 2);
  u16* wqb_b  = (u16*)alloc((size_t)NH * QKH * QR * 2);
  u16* wkva_b = (u16*)alloc((size_t)576 * DIM * 2);
  u16* qn     = (u16*)alloc((size_t)NTOK * QR * 2);
  float* C1   = (float*)alloc((size_t)NTOK * QR * 4);
  u16* C2b    = (u16*)alloc((size_t)NTOK * NH * QKH * 2);

  cvt_bf16<<<(NTOK * DIM) / 2048, 256, 0, stream>>>(x, x_bf, NTOK * DIM);
  cvt_bf16<<<(QR * DIM) / 2048, 256, 0, stream>>>(wqa, wqa_b, QR * DIM);
  cvt_bf16<<<(NH * QKH * QR) / 2048, 256, 0, stream>>>(wqb, wqb_b, NH * QKH * QR);
  cvt_bf16<<<(576 * DIM) / 2048, 256, 0, stream>>>(wkva, wkva_b, 576 * DIM);
  cvt_bf16<<<(DIM * DIM) / 2048, 256, 0, stream>>>(wo, wo_b, DIM * DIM);
  prep_wkvb<<<(NH * 256 * KVR) / 256, 256, 0, stream>>>(wkvb, wbkt, wbv);

  gemm_bt<false><<<dim3(QR / 128, NTOK / 128, 1), 256, 0, stream>>>(
      x_bf, wqa_b, C1, NTOK, QR, DIM, DIM, DIM, QR, 0, 0, 0);
  rms_q_kernel<<<NTOK, 256, 0, stream>>>(C1, qnw, qn);
  gemm_bt<true><<<dim3(NH * QKH / 128, NTOK / 128, 1), 256, 0, stream>>>(
      qn, wqb_b, C2b, NTOK, NH * QKH, QR, QR, QR, NH * QKH, 0, 0, 0);
  post_q_kernel<<<NTOK, 256, 0, stream>>>(C2b, fc, fs, qnope, qpe);
  gemm_bt<false><<<dim3(5, NTOK / 128, 1), 256, 0, stream>>>(
      x_bf, wkva_b, C1, NTOK, 576, DIM, DIM, DIM, 576, 0, 0, 0);
  post_kv_kernel<<<NTOK, 256, 0, stream>>>(C1, kvnw, fc, fs, kv_sw, kvt, kpe_sw);
  gemm_bt<true><<<dim3(KVR / 128, NTOK / 128, NH), 256, 0, stream>>>(
      qnope, wbkt, qlat, NTOK, KVR, NOPE, NOPE, NOPE, KVR,
      (long)NTOK * NOPE, (long)KVR * NOPE, (long)NTOK * KVR);
  attn_kernel<<<dim3(256, 1, 1), 512, 0, stream>>>(
      qlat, qpe, kv_sw, kvt, kpe_sw, olat);
  gemm_bt<true><<<dim3(1, NTOK / 128, NH), 256, 0, stream>>>(
      olat, wbv, oflat, NTOK, VH, KVR, KVR, KVR, DIM,
      (long)NTOK * KVR, (long)VH * KVR, (long)VH);
  gemm_bt<false><<<dim3(DIM / 128, NTOK / 128, 1), 256, 0, stream>>>(
      oflat, wo_b, out, NTOK, DIM, DIM, DIM, DIM, DIM, 0, 0, 0);
}